// Round 6
// baseline (152.791 us; speedup 1.0000x reference)
//
#include <hip/hip_runtime.h>
#include <stdint.h>

#define N_NODES 8192
#define KPAD 272
#define OUTC 384

typedef __attribute__((ext_vector_type(8))) short bhalf8;
typedef __attribute__((ext_vector_type(16))) float f32x16;
typedef __attribute__((ext_vector_type(4))) float f32x4;

__device__ inline unsigned short f2bf_rne(float f) {
    unsigned u = __builtin_bit_cast(unsigned, f);
    u += 0x7FFFu + ((u >> 16) & 1u);
    return (unsigned short)(u >> 16);
}

__device__ inline bhalf8 mk8(unsigned a, unsigned b, unsigned c, unsigned d) {
    union { unsigned u[4]; bhalf8 v; } U;
    U.u[0] = a; U.u[1] = b; U.u[2] = c; U.u[3] = d;
    return U.v;
}

// v_permlane32_swap_b32 a, b:  a = {a_lo, b_lo}, b = {a_hi, b_hi}  (rows = 32-lane halves)
__device__ inline void pl32swap(unsigned& a, unsigned& b) {
    asm("v_permlane32_swap_b32 %0, %1" : "+v"(a), "+v"(b));
}

#define GLD_TO_LDS(gptr, lptr)                                                              \
    __builtin_amdgcn_global_load_lds((const __attribute__((address_space(1))) void*)(gptr), \
                                     (__attribute__((address_space(3))) void*)(lptr), 16, 0, 0)

// ---------------- prep (weights only): WcatT, WrT, bcat ----------------
__global__ void k_prep(const float* __restrict__ Wi, const float* __restrict__ bi,
                       const float* __restrict__ Wj, const float* __restrict__ bj,
                       const float* __restrict__ Wk, const float* __restrict__ bk,
                       const float* __restrict__ Wr,
                       unsigned short* __restrict__ WcatT, unsigned short* __restrict__ WrT,
                       float* __restrict__ bcat) {
    int idx = blockIdx.x * 256 + threadIdx.x;
    const int WC_N = OUTC * KPAD;      // 104,448
    const int WR_N = 256 * 128;        // 32,768
    if (idx < WC_N) {
        int n = idx / KPAD, kk = idx - n * KPAD;
        int sel = n >> 7, d = n & 127;
        const float* W = (sel == 0) ? Wi : ((sel == 1) ? Wj : Wk);
        float v = 0.f;
        if (kk < 256) v = W[(kk + 3) * 128 + d];
        else if (kk < 259) v = W[(kk - 256) * 128 + d];
        WcatT[idx] = f2bf_rne(v);
        return;
    }
    idx -= WC_N;
    if (idx < WR_N) {
        int c = idx >> 7, d = idx & 127;
        WrT[idx] = f2bf_rne(Wr[d * 256 + c]);
        return;
    }
    idx -= WR_N;
    if (idx < OUTC) {
        float v = (idx < 128) ? bi[idx] : ((idx < 256) ? bj[idx - 128] : bk[idx - 256]);
        bcat[idx] = v;
    }
}

// ---------------- k1: projections straight from f32 inputs -> fi, fj, fkT ----------------
__global__ __launch_bounds__(256) void k_proj(const float* __restrict__ landmarks,
                                              const float* __restrict__ features,
                                              const unsigned short* __restrict__ WcatT,
                                              const float* __restrict__ bcat,
                                              unsigned short* __restrict__ fi,
                                              unsigned short* __restrict__ fj,
                                              unsigned short* __restrict__ fkT) {
    const int tid = threadIdx.x, w = tid >> 6, l = tid & 63, h = l >> 5, ln = l & 31;
    const unsigned bid = blockIdx.x;
    const int it = bid / 3, ng = bid - it * 3;
    const int i0 = it * 32;
    const int n = ng * 128 + w * 32 + ln;
    const int row = i0 + ln;
    f32x16 acc = {};
#pragma unroll
    for (int s = 0; s < 17; ++s) {
        union { unsigned short us[8]; bhalf8 v; } A;
        if (s < 16) {
            const float* fp = features + (size_t)row * 256 + s * 16 + h * 8;
            f32x4 v0 = *(const f32x4*)(fp);
            f32x4 v1 = *(const f32x4*)(fp + 4);
#pragma unroll
            for (int e = 0; e < 4; ++e) { A.us[e] = f2bf_rne(v0[e]); A.us[4 + e] = f2bf_rne(v1[e]); }
        } else {
#pragma unroll
            for (int e = 0; e < 8; ++e) A.us[e] = 0;
            if (h == 0) {
                A.us[0] = f2bf_rne(landmarks[row * 3 + 0]);
                A.us[1] = f2bf_rne(landmarks[row * 3 + 1]);
                A.us[2] = f2bf_rne(landmarks[row * 3 + 2]);
            }
        }
        bhalf8 b = *(const bhalf8*)(WcatT + (size_t)n * KPAD + s * 16 + h * 8);
        acc = __builtin_amdgcn_mfma_f32_32x32x16_bf16(A.v, b, acc, 0, 0, 0);
    }
    const int d = w * 32 + ln;
    const float bias = bcat[n];
    if (ng < 2) {
        unsigned short* dst = ng ? fj : fi;
#pragma unroll
        for (int q = 0; q < 4; ++q) {
            int ib = i0 + 8 * q + 4 * h;
#pragma unroll
            for (int r = 0; r < 4; ++r)
                dst[(size_t)(ib + r) * 128 + d] = f2bf_rne(acc[4 * q + r] + bias);
        }
    } else {
#pragma unroll
        for (int q = 0; q < 4; ++q) {
            int ib = i0 + 8 * q + 4 * h;
            ushort4 pk;
            pk.x = f2bf_rne(acc[4 * q + 0] + bias);
            pk.y = f2bf_rne(acc[4 * q + 1] + bias);
            pk.z = f2bf_rne(acc[4 * q + 2] + bias);
            pk.w = f2bf_rne(acc[4 * q + 3] + bias);
            *(ushort4*)(fkT + (size_t)d * N_NODES + ib) = pk;
        }
    }
}

// ---------------- k2: fused sigmoid-attention, 64-i blocks, T15 two-chunk pipeline ----------
// Iteration n: STAGE(n+1) | QK(n) [results used next iter] | sigmoid(n-1) [data ready, no
// dep-stall, overlaps QK(n) MFMA execution] | PV(n-1) [fk from regs loaded last iter] |
// fkregs <- fk(n) | barrier.  Accumulation order identical to the sequential version.
__global__ __launch_bounds__(256, 2) void k_attn(const unsigned short* __restrict__ fi,
                                                 const unsigned short* __restrict__ fj,
                                                 const unsigned short* __restrict__ fkT,
                                                 float* __restrict__ num_part,
                                                 float* __restrict__ den_part) {
    __shared__ __align__(16) char smem[65536];
    char* const fjb0 = smem;             // 16 KB
    char* const fkb0 = smem + 16384;     // 16 KB
    char* const fjb1 = smem + 32768;
    char* const fkb1 = smem + 49152;

    const int tid = threadIdx.x;
    const int w = tid >> 6, l = tid & 63, h = l >> 5, ln = l & 31;
    const int ih = w >> 1, jh = w & 1;
    const unsigned b = blockIdx.x;             // 512 blocks; xcd = b & 7 (round-robin)
    const int xcd = b & 7;
    const int jq = xcd >> 1;                   // one jq per XCD-pair
    const int rt = (int)(b >> 3) + ((xcd & 1) << 6);
    const int i0 = rt * 64;
    const int jbase = jq * 2048;

    const int rsub = l >> 4, cph = l & 15;

    // hoist fi B-fragments for this wave's 32-i block (32 VGPRs), reused across all j
    bhalf8 bfi[8];
#pragma unroll
    for (int s = 0; s < 8; ++s)
        bfi[s] = *(const bhalf8*)(fi + (size_t)(i0 + ih * 32 + ln) * 128 + s * 16 + h * 8);

    f32x16 acc[4] = {};   // numT partials: [d-tile 0..3][wave's 32 i], over wave's jh half
    float dacc = 0.f;

    // pipeline state
    f32x16 saA = {}, sbA = {}, saB = {}, sbB = {};   // score banks (even / odd chunks)
    bhalf8 fkA[4], fkB[4];                           // fk fragments of the current chunk
    bhalf8 fb0, fb1;                                 // packed P^T fragments of prev chunk

    auto STAGE = [&](char* fjd, char* fkd, int J0) {
#pragma unroll
        for (int q = 0; q < 4; ++q) {
            int r = w * 16 + q * 4 + rsub;
            int c = cph ^ (r & 15);
            GLD_TO_LDS(fj + (size_t)(J0 + r) * 128 + c * 8, fjd + (w * 16 + q * 4) * 256);
        }
#pragma unroll
        for (int q = 0; q < 4; ++q) {
            int r = w * 16 + q * 4 + rsub;
            int g = cph ^ (r & 15);
            int d = r + ((g >> 3) << 6);
            int joff = (g & 7) * 8;
            GLD_TO_LDS(fkT + (size_t)d * N_NODES + J0 + joff, fkd + (w * 16 + q * 4) * 256);
        }
    };

    // QK: S^T quadrant = fj[jh half] @ fi[ih half]^T, split accumulators (two 4-chains)
    auto QK = [&](const char* fjbuf, f32x16& sa, f32x16& sb) {
        const int jrow = jh * 32 + ln;
        f32x16 ta = {}, tb = {};
        __builtin_amdgcn_s_setprio(1);
#pragma unroll
        for (int ss = 0; ss < 4; ++ss) {
            int se = 2 * ss, so = 2 * ss + 1;
            int ce = (se * 2 + h) ^ (jrow & 15);
            int co = (so * 2 + h) ^ (jrow & 15);
            bhalf8 ae = *(const bhalf8*)(fjbuf + jrow * 256 + ce * 16);
            bhalf8 ao = *(const bhalf8*)(fjbuf + jrow * 256 + co * 16);
            ta = __builtin_amdgcn_mfma_f32_32x32x16_bf16(ae, bfi[se], ta, 0, 0, 0);
            tb = __builtin_amdgcn_mfma_f32_32x32x16_bf16(ao, bfi[so], tb, 0, 0, 0);
        }
        __builtin_amdgcn_s_setprio(0);
        sa = ta; sb = tb;
    };

    // SIG: sigmoid + denom accumulate + pack -> fb0/fb1 (identical op order to R4)
    auto SIG = [&](const f32x16& sa, const f32x16& sb) {
        unsigned p[8];
#pragma unroll
        for (int q = 0; q < 8; ++q) {
            float e0 = sa[2 * q] + sb[2 * q];
            float e1 = sa[2 * q + 1] + sb[2 * q + 1];
            float x0 = __builtin_amdgcn_rcpf(1.f + __builtin_amdgcn_exp2f(e0 * -1.44269504f));
            float x1 = __builtin_amdgcn_rcpf(1.f + __builtin_amdgcn_exp2f(e1 * -1.44269504f));
            dacc += x0;
            dacc += x1;
            p[q] = __builtin_amdgcn_perm(__builtin_bit_cast(unsigned, x1),
                                         __builtin_bit_cast(unsigned, x0), 0x07060302u);
        }
        unsigned w0 = p[0], w2 = p[2]; pl32swap(w0, w2);
        unsigned w1 = p[1], w3 = p[3]; pl32swap(w1, w3);
        fb0 = mk8(w0, w1, w2, w3);
        unsigned w4 = p[4], w6 = p[6]; pl32swap(w4, w6);
        unsigned w5 = p[5], w7 = p[7]; pl32swap(w5, w7);
        fb1 = mk8(w4, w5, w6, w7);
    };

    // PV: numT += fk * P^T   (fk fragments from registers; same MFMA order as R4)
    auto PV = [&]() {
        __builtin_amdgcn_s_setprio(1);
#pragma unroll
        for (int m4 = 0; m4 < 4; ++m4)
            acc[m4] = __builtin_amdgcn_mfma_f32_32x32x16_bf16(fkA[m4], fb0, acc[m4], 0, 0, 0);
#pragma unroll
        for (int m4 = 0; m4 < 4; ++m4)
            acc[m4] = __builtin_amdgcn_mfma_f32_32x32x16_bf16(fkB[m4], fb1, acc[m4], 0, 0, 0);
        __builtin_amdgcn_s_setprio(0);
    };

    // LOADFK: fk fragments of the current chunk -> registers (for next iteration's PV)
    auto LOADFK = [&](const char* fkbuf) {
#pragma unroll
        for (int m4 = 0; m4 < 4; ++m4) {
            int d = m4 * 32 + ln;
            int r = d & 63;
            int ghi = (d >> 6) << 3;
            int gA = ghi | (jh * 4 + h);
            int gB = ghi | (jh * 4 + 2 + h);
            fkA[m4] = *(const bhalf8*)(fkbuf + r * 256 + (gA ^ (r & 15)) * 16);
            fkB[m4] = *(const bhalf8*)(fkbuf + r * 256 + (gB ^ (r & 15)) * 16);
        }
    };

    // -------- pipeline --------
    STAGE(fjb0, fkb0, jbase);
    __syncthreads();
    // iter 0 (even, buf0): no sig/PV yet
    STAGE(fjb1, fkb1, jbase + 64);
    QK(fjb0, saA, sbA);
    LOADFK(fkb0);
    __syncthreads();
#pragma unroll 1
    for (int k = 1; k < 31; k += 2) {
        // iter k (odd, buf1)
        STAGE(fjb0, fkb0, jbase + (k + 1) * 64);
        QK(fjb1, saB, sbB);
        SIG(saA, sbA);      // chunk k-1
        PV();
        LOADFK(fkb1);
        __syncthreads();
        // iter k+1 (even, buf0)
        if (k + 1 < 31) STAGE(fjb1, fkb1, jbase + (k + 2) * 64);
        QK(fjb0, saA, sbA);
        SIG(saB, sbB);      // chunk k
        PV();
        LOADFK(fkb0);
        __syncthreads();
    }
    // iter 31 (odd, buf1)
    QK(fjb1, saB, sbB);
    SIG(saA, sbA);          // chunk 30
    PV();
    LOADFK(fkb1);
    // drain: chunk 31
    SIG(saB, sbB);
    PV();
    __syncthreads();        // all LDS reads done before epilogue reuses smem

    // denom: fold lane l <-> l^32 (h halves), stash per wave
    dacc += __shfl_xor(dacc, 32, 64);
    float* denb = (float*)(smem + 40960);   // 128 floats, disjoint from reduce buf
    if (h == 0) denb[w * 32 + ln] = dacc;

    // num reduce: jh=0 waves write [64 i][128 d] (pad 132), jh=1 waves add
    float* buf = (float*)smem;
    if (jh == 0) {
#pragma unroll
        for (int m4 = 0; m4 < 4; ++m4)
#pragma unroll
            for (int q = 0; q < 4; ++q) {
                f32x4 v = {acc[m4][4 * q + 0], acc[m4][4 * q + 1],
                           acc[m4][4 * q + 2], acc[m4][4 * q + 3]};
                *(f32x4*)(buf + (ih * 32 + ln) * 132 + m4 * 32 + 8 * q + 4 * h) = v;
            }
    }
    __syncthreads();
    if (jh == 1) {
#pragma unroll
        for (int m4 = 0; m4 < 4; ++m4)
#pragma unroll
            for (int q = 0; q < 4; ++q) {
                float* p4 = buf + (ih * 32 + ln) * 132 + m4 * 32 + 8 * q + 4 * h;
                f32x4 old = *(f32x4*)p4;
                f32x4 v = {acc[m4][4 * q + 0], acc[m4][4 * q + 1],
                           acc[m4][4 * q + 2], acc[m4][4 * q + 3]};
                *(f32x4*)p4 = old + v;
            }
    }
    __syncthreads();
#pragma unroll
    for (int e = 0; e < 8; ++e) {
        int v = e * 256 + tid;                 // 2048 float4s = 64 i x 32
        int iloc = v >> 5, d4 = (v & 31) * 4;
        *(f32x4*)(num_part + ((size_t)jq * N_NODES + i0 + iloc) * 128 + d4) =
            *(const f32x4*)(buf + iloc * 132 + d4);
    }
    if (tid < 64) {
        den_part[(size_t)jq * N_NODES + i0 + tid] =
            denb[(tid >> 5) * 64 + (tid & 31)] + denb[(tid >> 5) * 64 + 32 + (tid & 31)];
    }
}

// ---------------- k3: t = (sum num)/(sum den); out = t @ Wr + br + features ----------------
__global__ __launch_bounds__(256) void k_out(const unsigned short* __restrict__ WrT,
                                             const float* __restrict__ br,
                                             const float* __restrict__ features,
                                             const float* __restrict__ num_part,
                                             const float* __restrict__ den_part,
                                             float* __restrict__ out) {
    __shared__ __align__(16) char smem[73728];
    char* const tb = smem + 65536;   // t tile [32 i][256 B] swizzled, 8 KB
    const int tid = threadIdx.x, w = tid >> 6, l = tid & 63, h = l >> 5, ln = l & 31;
    const int i0 = blockIdx.x * 32;
    // stage WrT (64 KB) async into smem[0..64K)
    {
        int rsub = l >> 4, cph = l & 15;
#pragma unroll
        for (int q = 0; q < 16; ++q) {
            int r = w * 64 + q * 4 + rsub;
            int c = cph ^ (r & 15);
            GLD_TO_LDS(WrT + (size_t)r * 128 + c * 8, (char*)smem + (w * 64 + q * 4) * 256);
        }
    }
    // combine num/den partials -> t tile (bf16) while staging lands
    {
        int i = tid >> 3, dseg = (tid & 7) * 16;
        f32x4 s[4] = {};
        float ds = 0.f;
#pragma unroll
        for (int q = 0; q < 4; ++q) {
            const float* np = num_part + ((size_t)(q * N_NODES + i0 + i)) * 128 + dseg;
#pragma unroll
            for (int k = 0; k < 4; ++k) s[k] += *(const f32x4*)(np + 4 * k);
            ds += den_part[(size_t)q * N_NODES + i0 + i];
        }
        float inv = 1.0f / ds;
#pragma unroll
        for (int cc = 0; cc < 2; ++cc) {
            union { unsigned u[4]; bhalf8 v; } U;
#pragma unroll
            for (int m = 0; m < 4; ++m) {
                int e0 = cc * 8 + 2 * m;
                unsigned lo = f2bf_rne(s[e0 >> 2][e0 & 3] * inv);
                unsigned hi = f2bf_rne(s[(e0 + 1) >> 2][(e0 + 1) & 3] * inv);
                U.u[m] = lo | (hi << 16);
            }
            int slot = ((tid & 7) * 2 + cc) ^ (i & 15);
            *(bhalf8*)(tb + i * 256 + slot * 16) = U.v;
        }
    }
    __syncthreads();
    f32x16 acc[2] = {};
#pragma unroll
    for (int s = 0; s < 8; ++s) {
        int ca = (s * 2 + h) ^ (ln & 15);
        bhalf8 af = *(const bhalf8*)(tb + ln * 256 + ca * 16);
#pragma unroll
        for (int nt = 0; nt < 2; ++nt) {
            int row = w * 64 + nt * 32 + ln;
            int c = (s * 2 + h) ^ (row & 15);
            bhalf8 bf = *(const bhalf8*)(smem + row * 256 + c * 16);
            acc[nt] = __builtin_amdgcn_mfma_f32_32x32x16_bf16(af, bf, acc[nt], 0, 0, 0);
        }
    }
#pragma unroll
    for (int nt = 0; nt < 2; ++nt) {
        int cc = w * 64 + nt * 32 + ln;
        float bias = br[cc];
#pragma unroll
        for (int q = 0; q < 4; ++q) {
#pragma unroll
            for (int r = 0; r < 4; ++r) {
                int i = i0 + 8 * q + 4 * h + r;
                out[(size_t)i * 256 + cc] = acc[nt][4 * q + r] + bias + features[(size_t)i * 256 + cc];
            }
        }
    }
}

extern "C" void kernel_launch(void* const* d_in, const int* in_sizes, int n_in,
                              void* d_out, int out_size, void* d_ws, size_t ws_size,
                              hipStream_t stream) {
    const float* landmarks = (const float*)d_in[0];
    const float* features  = (const float*)d_in[1];
    const float* Wi = (const float*)d_in[2];
    const float* bi = (const float*)d_in[3];
    const float* Wj = (const float*)d_in[4];
    const float* bj = (const float*)d_in[5];
    const float* Wk = (const float*)d_in[6];
    const float* bk = (const float*)d_in[7];
    const float* Wr = (const float*)d_in[8];
    const float* br = (const float*)d_in[9];

    char* ws = (char*)d_ws;
    unsigned short* WcatT   = (unsigned short*)(ws + 0);         // 384x272 bf16   (208,896 B)
    unsigned short* WrT     = (unsigned short*)(ws + 208896);    // 256x128 bf16   (65,536 B)
    float*          bcat    = (float*)(ws + 274432);             // 384 f32        (1,536 B)
    unsigned short* fi      = (unsigned short*)(ws + 275968);    // 8192x128 bf16  (2,097,152 B)
    unsigned short* fjp     = (unsigned short*)(ws + 2373120);   // 8192x128 bf16
    unsigned short* fkT     = (unsigned short*)(ws + 4470272);   // 128x8192 bf16
    float*          num_part= (float*)(ws + 6567424);            // 4x8192x128 f32 (16,777,216 B)
    float*          den_part= (float*)(ws + 23344640);           // 4x8192 f32     (131,072 B)

    float* out = (float*)d_out;

    hipLaunchKernelGGL(k_prep, dim3(538), dim3(256), 0, stream,
                       Wi, bi, Wj, bj, Wk, bk, Wr, WcatT, WrT, bcat);
    hipLaunchKernelGGL(k_proj, dim3(768), dim3(256), 0, stream,
                       landmarks, features, WcatT, bcat, fi, fjp, fkT);
    hipLaunchKernelGGL(k_attn, dim3(512), dim3(256), 0, stream, fi, fjp, fkT, num_part, den_part);
    hipLaunchKernelGGL(k_out, dim3(256), dim3(256), 0, stream,
                       WrT, br, features, num_part, den_part, out);
}

// Round 7
// 150.977 us; speedup vs baseline: 1.0120x; 1.0120x over previous
//
#include <hip/hip_runtime.h>
#include <stdint.h>

#define N_NODES 8192
#define KPAD 272
#define OUTC 384

typedef __attribute__((ext_vector_type(8))) short bhalf8;
typedef __attribute__((ext_vector_type(16))) float f32x16;
typedef __attribute__((ext_vector_type(4))) float f32x4;

__device__ inline unsigned short f2bf_rne(float f) {
    unsigned u = __builtin_bit_cast(unsigned, f);
    u += 0x7FFFu + ((u >> 16) & 1u);
    return (unsigned short)(u >> 16);
}

__device__ inline bhalf8 mk8(unsigned a, unsigned b, unsigned c, unsigned d) {
    union { unsigned u[4]; bhalf8 v; } U;
    U.u[0] = a; U.u[1] = b; U.u[2] = c; U.u[3] = d;
    return U.v;
}

// v_permlane32_swap_b32 a, b:  a = {a_lo, b_lo}, b = {a_hi, b_hi}  (rows = 32-lane halves)
__device__ inline void pl32swap(unsigned& a, unsigned& b) {
    asm("v_permlane32_swap_b32 %0, %1" : "+v"(a), "+v"(b));
}

#define GLD_TO_LDS(gptr, lptr)                                                              \
    __builtin_amdgcn_global_load_lds((const __attribute__((address_space(1))) void*)(gptr), \
                                     (__attribute__((address_space(3))) void*)(lptr), 16, 0, 0)

// ---------------- prep (weights only): WcatT, WrT, bcat ----------------
__global__ void k_prep(const float* __restrict__ Wi, const float* __restrict__ bi,
                       const float* __restrict__ Wj, const float* __restrict__ bj,
                       const float* __restrict__ Wk, const float* __restrict__ bk,
                       const float* __restrict__ Wr,
                       unsigned short* __restrict__ WcatT, unsigned short* __restrict__ WrT,
                       float* __restrict__ bcat) {
    int idx = blockIdx.x * 256 + threadIdx.x;
    const int WC_N = OUTC * KPAD;      // 104,448
    const int WR_N = 256 * 128;        // 32,768
    if (idx < WC_N) {
        int n = idx / KPAD, kk = idx - n * KPAD;
        int sel = n >> 7, d = n & 127;
        const float* W = (sel == 0) ? Wi : ((sel == 1) ? Wj : Wk);
        float v = 0.f;
        if (kk < 256) v = W[(kk + 3) * 128 + d];
        else if (kk < 259) v = W[(kk - 256) * 128 + d];
        WcatT[idx] = f2bf_rne(v);
        return;
    }
    idx -= WC_N;
    if (idx < WR_N) {
        int c = idx >> 7, d = idx & 127;
        WrT[idx] = f2bf_rne(Wr[d * 256 + c]);
        return;
    }
    idx -= WR_N;
    if (idx < OUTC) {
        float v = (idx < 128) ? bi[idx] : ((idx < 256) ? bj[idx - 128] : bk[idx - 256]);
        bcat[idx] = v;
    }
}

// ---------------- k1: projections from f32 inputs -> fi (natural), fjF, fkF (fragment-major)
// fjF layout: chunk c (64 j) x k-chunk kc (8 k) x 64 j-rows x 16 B:
//   ushort idx = (j>>6)*8192 + (k>>3)*512 + (j&63)*8 + (k&7)
// fkF layout: chunk c x j-slice s (8 j) x 128 d-rows x 16 B:
//   ushort idx = (j>>6)*8192 + ((j>>3)&7)*1024 + d*8 + (j&7)
__global__ __launch_bounds__(256) void k_proj(const float* __restrict__ landmarks,
                                              const float* __restrict__ features,
                                              const unsigned short* __restrict__ WcatT,
                                              const float* __restrict__ bcat,
                                              unsigned short* __restrict__ fi,
                                              unsigned short* __restrict__ fjF,
                                              unsigned short* __restrict__ fkF) {
    const int tid = threadIdx.x, w = tid >> 6, l = tid & 63, h = l >> 5, ln = l & 31;
    const unsigned bid = blockIdx.x;
    const int it = bid / 3, ng = bid - it * 3;
    const int i0 = it * 32;
    const int n = ng * 128 + w * 32 + ln;
    const int row = i0 + ln;
    f32x16 acc = {};
#pragma unroll
    for (int s = 0; s < 17; ++s) {
        union { unsigned short us[8]; bhalf8 v; } A;
        if (s < 16) {
            const float* fp = features + (size_t)row * 256 + s * 16 + h * 8;
            f32x4 v0 = *(const f32x4*)(fp);
            f32x4 v1 = *(const f32x4*)(fp + 4);
#pragma unroll
            for (int e = 0; e < 4; ++e) { A.us[e] = f2bf_rne(v0[e]); A.us[4 + e] = f2bf_rne(v1[e]); }
        } else {
#pragma unroll
            for (int e = 0; e < 8; ++e) A.us[e] = 0;
            if (h == 0) {
                A.us[0] = f2bf_rne(landmarks[row * 3 + 0]);
                A.us[1] = f2bf_rne(landmarks[row * 3 + 1]);
                A.us[2] = f2bf_rne(landmarks[row * 3 + 2]);
            }
        }
        bhalf8 b = *(const bhalf8*)(WcatT + (size_t)n * KPAD + s * 16 + h * 8);
        acc = __builtin_amdgcn_mfma_f32_32x32x16_bf16(A.v, b, acc, 0, 0, 0);
    }
    const int d = w * 32 + ln;
    const float bias = bcat[n];
    if (ng == 0) {
#pragma unroll
        for (int q = 0; q < 4; ++q) {
            int ib = i0 + 8 * q + 4 * h;
#pragma unroll
            for (int r = 0; r < 4; ++r)
                fi[(size_t)(ib + r) * 128 + d] = f2bf_rne(acc[4 * q + r] + bias);
        }
    } else if (ng == 1) {
#pragma unroll
        for (int q = 0; q < 4; ++q) {
            int ib = i0 + 8 * q + 4 * h;
#pragma unroll
            for (int r = 0; r < 4; ++r) {
                int j = ib + r;
                fjF[(size_t)(j >> 6) * 8192 + (d >> 3) * 512 + (j & 63) * 8 + (d & 7)] =
                    f2bf_rne(acc[4 * q + r] + bias);
            }
        }
    } else {
#pragma unroll
        for (int q = 0; q < 4; ++q) {
            int ib = i0 + 8 * q + 4 * h;
            ushort4 pk;
            pk.x = f2bf_rne(acc[4 * q + 0] + bias);
            pk.y = f2bf_rne(acc[4 * q + 1] + bias);
            pk.z = f2bf_rne(acc[4 * q + 2] + bias);
            pk.w = f2bf_rne(acc[4 * q + 3] + bias);
            *(ushort4*)(fkF + (size_t)(ib >> 6) * 8192 + ((ib >> 3) & 7) * 1024 + d * 8 + 4 * h) = pk;
        }
    }
}

// ---------------- k2: fused sigmoid-attention — barrier-free streaming main loop ----------
// No LDS, no __syncthreads in the loop: fragment-major fjF/fkF feed MFMA operands via
// coalesced global loads (L2-resident per XCD). Each wave free-runs; prefetch of chunk n+1
// issues mid-chunk n, so a full chunk of MFMA+VALU covers the load latency.
__global__ __launch_bounds__(256, 2) void k_attn(const unsigned short* __restrict__ fi,
                                                 const unsigned short* __restrict__ fjF,
                                                 const unsigned short* __restrict__ fkF,
                                                 float* __restrict__ num_part,
                                                 float* __restrict__ den_part) {
    __shared__ __align__(16) char smem[36864];   // epilogue reduce buffer only

    const int tid = threadIdx.x;
    const int w = tid >> 6, l = tid & 63, h = l >> 5, ln = l & 31;
    const int ih = w >> 1, jh = w & 1;
    const unsigned b = blockIdx.x;             // 512 blocks; xcd = b & 7 (round-robin)
    const int xcd = b & 7;
    const int jq = xcd >> 1;                   // one jq per XCD-pair (L2 locality, R4-proven)
    const int rt = (int)(b >> 3) + ((xcd & 1) << 6);
    const int i0 = rt * 64;

    // hoist fi B-fragments for this wave's 32-i block (32 VGPRs), reused across all j
    bhalf8 bfi[8];
#pragma unroll
    for (int s = 0; s < 8; ++s)
        bfi[s] = *(const bhalf8*)(fi + (size_t)(i0 + ih * 32 + ln) * 128 + s * 16 + h * 8);

    f32x16 acc[4] = {};   // numT partials: [d-tile 0..3][wave's 32 i], over wave's jh half
    float dacc = 0.f;

    // per-lane fragment base pointers (ushort units); chunk stride = 8192 ushorts (16 KB)
    const unsigned short* fjp = fjF + (size_t)(jq * 32) * 8192 + (jh * 32 + ln) * 8 + h * 512;
    const unsigned short* fkp = fkF + (size_t)(jq * 32) * 8192 + (jh * 4 + h) * 1024 + ln * 8;

    bhalf8 fjc[8];          // QK A-fragments of current chunk (fjc[2ss]=kc 4ss+h, [2ss+1]=4ss+2+h)
    bhalf8 fkA[4], fkB[4];  // PV fk fragments of current chunk

    auto LOADFJ = [&](const unsigned short* p) {
#pragma unroll
        for (int ss = 0; ss < 4; ++ss) {
            fjc[2 * ss]     = *(const bhalf8*)(p + ss * 2048);
            fjc[2 * ss + 1] = *(const bhalf8*)(p + ss * 2048 + 1024);
        }
    };
    auto LOADFK = [&](const unsigned short* p) {
#pragma unroll
        for (int m4 = 0; m4 < 4; ++m4) {
            fkA[m4] = *(const bhalf8*)(p + m4 * 256);
            fkB[m4] = *(const bhalf8*)(p + 2048 + m4 * 256);
        }
    };

    LOADFJ(fjp);
    LOADFK(fkp);
#pragma unroll 1
    for (int mt = 0; mt < 32; ++mt) {
        // QK: S^T quadrant = fj[jh half] @ fi[ih half]^T (two interleaved 4-chains)
        f32x16 sa = {}, sb = {};
        __builtin_amdgcn_s_setprio(1);
#pragma unroll
        for (int ss = 0; ss < 4; ++ss) {
            sa = __builtin_amdgcn_mfma_f32_32x32x16_bf16(fjc[2 * ss], bfi[2 * ss], sa, 0, 0, 0);
            sb = __builtin_amdgcn_mfma_f32_32x32x16_bf16(fjc[2 * ss + 1], bfi[2 * ss + 1], sb, 0, 0, 0);
        }
        __builtin_amdgcn_s_setprio(0);
        // prefetch next chunk's fj (mt=31 reads into the adjacent ws buffer — allocated, unused)
        fjp += 8192;
        LOADFJ(fjp);
        // sigmoid + denom accumulate + pack consecutive-j pairs to bf16 (order == R4)
        unsigned p[8];
#pragma unroll
        for (int q = 0; q < 8; ++q) {
            float e0 = sa[2 * q] + sb[2 * q];
            float e1 = sa[2 * q + 1] + sb[2 * q + 1];
            float x0 = __builtin_amdgcn_rcpf(1.f + __builtin_amdgcn_exp2f(e0 * -1.44269504f));
            float x1 = __builtin_amdgcn_rcpf(1.f + __builtin_amdgcn_exp2f(e1 * -1.44269504f));
            dacc += x0;
            dacc += x1;
            p[q] = __builtin_amdgcn_perm(__builtin_bit_cast(unsigned, x1),
                                         __builtin_bit_cast(unsigned, x0), 0x07060302u);
        }
        unsigned w0 = p[0], w2 = p[2]; pl32swap(w0, w2);
        unsigned w1 = p[1], w3 = p[3]; pl32swap(w1, w3);
        bhalf8 fb0 = mk8(w0, w1, w2, w3);
        unsigned w4 = p[4], w6 = p[6]; pl32swap(w4, w6);
        unsigned w5 = p[5], w7 = p[7]; pl32swap(w5, w7);
        bhalf8 fb1 = mk8(w4, w5, w6, w7);
        // PV: numT[d][i] += fk[d][j-slice] * P^T[j-slice][i]
        __builtin_amdgcn_s_setprio(1);
#pragma unroll
        for (int m4 = 0; m4 < 4; ++m4)
            acc[m4] = __builtin_amdgcn_mfma_f32_32x32x16_bf16(fkA[m4], fb0, acc[m4], 0, 0, 0);
#pragma unroll
        for (int m4 = 0; m4 < 4; ++m4)
            acc[m4] = __builtin_amdgcn_mfma_f32_32x32x16_bf16(fkB[m4], fb1, acc[m4], 0, 0, 0);
        __builtin_amdgcn_s_setprio(0);
        // prefetch next chunk's fk
        fkp += 8192;
        LOADFK(fkp);
    }

    // denom: fold lane l <-> l^32 (h halves), stash per wave
    dacc += __shfl_xor(dacc, 32, 64);
    float* denb = (float*)(smem + 34816);   // 128 floats, after the 34,816 B reduce buf
    if (h == 0) denb[w * 32 + ln] = dacc;

    // num reduce: jh=0 waves write [64 i][128 d] (pad 132), jh=1 waves add
    float* buf = (float*)smem;
    __syncthreads();   // harmless first barrier (no LDS used before)
    if (jh == 0) {
#pragma unroll
        for (int m4 = 0; m4 < 4; ++m4)
#pragma unroll
            for (int q = 0; q < 4; ++q) {
                f32x4 v = {acc[m4][4 * q + 0], acc[m4][4 * q + 1],
                           acc[m4][4 * q + 2], acc[m4][4 * q + 3]};
                *(f32x4*)(buf + (ih * 32 + ln) * 132 + m4 * 32 + 8 * q + 4 * h) = v;
            }
    }
    __syncthreads();
    if (jh == 1) {
#pragma unroll
        for (int m4 = 0; m4 < 4; ++m4)
#pragma unroll
            for (int q = 0; q < 4; ++q) {
                float* p4 = buf + (ih * 32 + ln) * 132 + m4 * 32 + 8 * q + 4 * h;
                f32x4 old = *(f32x4*)p4;
                f32x4 v = {acc[m4][4 * q + 0], acc[m4][4 * q + 1],
                           acc[m4][4 * q + 2], acc[m4][4 * q + 3]};
                *(f32x4*)p4 = old + v;
            }
    }
    __syncthreads();
#pragma unroll
    for (int e = 0; e < 8; ++e) {
        int v = e * 256 + tid;                 // 2048 float4s = 64 i x 32
        int iloc = v >> 5, d4 = (v & 31) * 4;
        *(f32x4*)(num_part + ((size_t)jq * N_NODES + i0 + iloc) * 128 + d4) =
            *(const f32x4*)(buf + iloc * 132 + d4);
    }
    if (tid < 64) {
        den_part[(size_t)jq * N_NODES + i0 + tid] =
            denb[(tid >> 5) * 64 + (tid & 31)] + denb[(tid >> 5) * 64 + 32 + (tid & 31)];
    }
}

// ---------------- k3: t = (sum num)/(sum den); out = t @ Wr + br + features ----------------
__global__ __launch_bounds__(256) void k_out(const unsigned short* __restrict__ WrT,
                                             const float* __restrict__ br,
                                             const float* __restrict__ features,
                                             const float* __restrict__ num_part,
                                             const float* __restrict__ den_part,
                                             float* __restrict__ out) {
    __shared__ __align__(16) char smem[73728];
    char* const tb = smem + 65536;   // t tile [32 i][256 B] swizzled, 8 KB
    const int tid = threadIdx.x, w = tid >> 6, l = tid & 63, h = l >> 5, ln = l & 31;
    const int i0 = blockIdx.x * 32;
    // stage WrT (64 KB) async into smem[0..64K)
    {
        int rsub = l >> 4, cph = l & 15;
#pragma unroll
        for (int q = 0; q < 16; ++q) {
            int r = w * 64 + q * 4 + rsub;
            int c = cph ^ (r & 15);
            GLD_TO_LDS(WrT + (size_t)r * 128 + c * 8, (char*)smem + (w * 64 + q * 4) * 256);
        }
    }
    // combine num/den partials -> t tile (bf16) while staging lands
    {
        int i = tid >> 3, dseg = (tid & 7) * 16;
        f32x4 s[4] = {};
        float ds = 0.f;
#pragma unroll
        for (int q = 0; q < 4; ++q) {
            const float* np = num_part + ((size_t)(q * N_NODES + i0 + i)) * 128 + dseg;
#pragma unroll
            for (int k = 0; k < 4; ++k) s[k] += *(const f32x4*)(np + 4 * k);
            ds += den_part[(size_t)q * N_NODES + i0 + i];
        }
        float inv = 1.0f / ds;
#pragma unroll
        for (int cc = 0; cc < 2; ++cc) {
            union { unsigned u[4]; bhalf8 v; } U;
#pragma unroll
            for (int m = 0; m < 4; ++m) {
                int e0 = cc * 8 + 2 * m;
                unsigned lo = f2bf_rne(s[e0 >> 2][e0 & 3] * inv);
                unsigned hi = f2bf_rne(s[(e0 + 1) >> 2][(e0 + 1) & 3] * inv);
                U.u[m] = lo | (hi << 16);
            }
            int slot = ((tid & 7) * 2 + cc) ^ (i & 15);
            *(bhalf8*)(tb + i * 256 + slot * 16) = U.v;
        }
    }
    __syncthreads();
    f32x16 acc[2] = {};
#pragma unroll
    for (int s = 0; s < 8; ++s) {
        int ca = (s * 2 + h) ^ (ln & 15);
        bhalf8 af = *(const bhalf8*)(tb + ln * 256 + ca * 16);
#pragma unroll
        for (int nt = 0; nt < 2; ++nt) {
            int row = w * 64 + nt * 32 + ln;
            int c = (s * 2 + h) ^ (row & 15);
            bhalf8 bf = *(const bhalf8*)(smem + row * 256 + c * 16);
            acc[nt] = __builtin_amdgcn_mfma_f32_32x32x16_bf16(af, bf, acc[nt], 0, 0, 0);
        }
    }
#pragma unroll
    for (int nt = 0; nt < 2; ++nt) {
        int cc = w * 64 + nt * 32 + ln;
        float bias = br[cc];
#pragma unroll
        for (int q = 0; q < 4; ++q) {
#pragma unroll
            for (int r = 0; r < 4; ++r) {
                int i = i0 + 8 * q + 4 * h + r;
                out[(size_t)i * 256 + cc] = acc[nt][4 * q + r] + bias + features[(size_t)i * 256 + cc];
            }
        }
    }
}

extern "C" void kernel_launch(void* const* d_in, const int* in_sizes, int n_in,
                              void* d_out, int out_size, void* d_ws, size_t ws_size,
                              hipStream_t stream) {
    const float* landmarks = (const float*)d_in[0];
    const float* features  = (const float*)d_in[1];
    const float* Wi = (const float*)d_in[2];
    const float* bi = (const float*)d_in[3];
    const float* Wj = (const float*)d_in[4];
    const float* bj = (const float*)d_in[5];
    const float* Wk = (const float*)d_in[6];
    const float* bk = (const float*)d_in[7];
    const float* Wr = (const float*)d_in[8];
    const float* br = (const float*)d_in[9];

    char* ws = (char*)d_ws;
    unsigned short* WcatT   = (unsigned short*)(ws + 0);         // 384x272 bf16   (208,896 B)
    unsigned short* WrT     = (unsigned short*)(ws + 208896);    // 256x128 bf16   (65,536 B)
    float*          bcat    = (float*)(ws + 274432);             // 384 f32        (1,536 B)
    unsigned short* fi      = (unsigned short*)(ws + 275968);    // 8192x128 bf16  (2,097,152 B)
    unsigned short* fjF     = (unsigned short*)(ws + 2373120);   // fragment-major (2,097,152 B)
    unsigned short* fkF     = (unsigned short*)(ws + 4470272);   // fragment-major (2,097,152 B)
    float*          num_part= (float*)(ws + 6567424);            // 4x8192x128 f32 (16,777,216 B)
    float*          den_part= (float*)(ws + 23344640);           // 4x8192 f32     (131,072 B)

    float* out = (float*)d_out;

    hipLaunchKernelGGL(k_prep, dim3(538), dim3(256), 0, stream,
                       Wi, bi, Wj, bj, Wk, bk, Wr, WcatT, WrT, bcat);
    hipLaunchKernelGGL(k_proj, dim3(768), dim3(256), 0, stream,
                       landmarks, features, WcatT, bcat, fi, fjF, fkF);
    hipLaunchKernelGGL(k_attn, dim3(512), dim3(256), 0, stream, fi, fjF, fkF, num_part, den_part);
    hipLaunchKernelGGL(k_out, dim3(256), dim3(256), 0, stream,
                       WrT, br, features, num_part, den_part, out);
}